// Round 5
// baseline (236.571 us; speedup 1.0000x reference)
//
#include <hip/hip_runtime.h>

// Problem: B=1, S=4096, D=1024, H=16, hs=64. f32 in/out, f16 MFMA internally.
#define SEQ 4096
#define DM  1024
#define NH  16
#define HS  64
#define LDQK 2048   // Q|K stacked projection buffer row stride

typedef __attribute__((ext_vector_type(8))) _Float16 f16x8;
typedef __attribute__((ext_vector_type(4))) _Float16 f16x4;
typedef __attribute__((ext_vector_type(4))) float    f32x4;

#define MFMA16(a, b, c) __builtin_amdgcn_mfma_f32_16x16x32_f16((a), (b), (c), 0, 0, 0)

// DPP row_ror reduction across a 16-lane DPP row (epilogue only).
#define DPP_ROR_F(x, N) __int_as_float(__builtin_amdgcn_update_dpp( \
    0, __float_as_int(x), 0x120 + (N), 0xF, 0xF, false))

__device__ __forceinline__ float red16_add(float x) {
    x += DPP_ROR_F(x, 1);
    x += DPP_ROR_F(x, 2);
    x += DPP_ROR_F(x, 4);
    x += DPP_ROR_F(x, 8);
    return x;
}

// ---------------------------------------------------------------------------
// single cast launch: y=0 -> x (4M elems), y=1 -> 4 weights (1M each).
// wq/wk land stacked in wqkb[2048][1024] so Q,K project as ONE GEMM.
// ---------------------------------------------------------------------------
__global__ __launch_bounds__(256) void cast_all(
    const float* __restrict__ x,
    const float* __restrict__ wq, const float* __restrict__ wk,
    const float* __restrict__ wv, const float* __restrict__ wo,
    _Float16* __restrict__ xb, _Float16* __restrict__ wqkb,
    _Float16* __restrict__ wvb, _Float16* __restrict__ wob)
{
    const float* s; _Float16* d; int i;
    if (blockIdx.y == 0) {
        s = x; d = xb;
        i = blockIdx.x * 1024 + threadIdx.x * 4;
    } else {
        int wsel = blockIdx.x >> 10;       // 0..3
        int bx   = blockIdx.x & 1023;
        switch (wsel) {
            case 0:  s = wq; d = wqkb;               break;
            case 1:  s = wk; d = wqkb + (1u << 20);  break;  // rows 1024..2047
            case 2:  s = wv; d = wvb;                break;
            default: s = wo; d = wob;                break;
        }
        i = bx * 1024 + threadIdx.x * 4;
    }
    float4 v = *reinterpret_cast<const float4*>(s + i);
    f16x4 o = {(_Float16)v.x, (_Float16)v.y, (_Float16)v.z, (_Float16)v.w};
    *reinterpret_cast<f16x4*>(d + i) = o;
}

// ---------------------------------------------------------------------------
// MFMA GEMM: C[M][N] = (A[M][K] @ W[N][K]^T + bias) * scale
// 64x128 tile, BK=64, 256 threads = 4 waves (2x2 of 32x64), 2x4 acc/wave.
// Register-prefetch staging. LDS stride 72 f16 (bank size-floor).
// ---------------------------------------------------------------------------
#define GPAD 72

template <int BIAS_ROW, typename OUT_T>
__global__ __launch_bounds__(256, 2) void gemm_bt_f16(
    const _Float16* __restrict__ A,    // [M][K]
    const _Float16* __restrict__ W,    // [N][K]
    const float*    __restrict__ bias_lo,
    const float*    __restrict__ bias_hi,
    OUT_T* __restrict__ C,             // [M][N]
    int M, int N, int K,
    float scale_lo, float scale_hi, int nsplit)
{
    __shared__ _Float16 As[64][GPAD];   //  9.2 KB
    __shared__ _Float16 Bs[128][GPAD];  // 18.4 KB

    const int t    = threadIdx.x;
    const int w    = t >> 6;
    const int lane = t & 63;
    const int q    = lane >> 4;
    const int l    = lane & 15;
    const int m0   = blockIdx.y * 64;
    const int n0   = blockIdx.x * 128;
    const int wm   = (w & 1) * 32;
    const int wn   = (w >> 1) * 64;

    const float* bias  = (n0 < nsplit) ? bias_lo : bias_hi;
    const int    nbase = (n0 < nsplit) ? 0 : nsplit;
    const float  scale = (n0 < nsplit) ? scale_lo : scale_hi;

    const int ar = t >> 2, ac = (t & 3) * 16;   // A: 64 rows x 64 cols, 2 uint4/thr
    const int br = t >> 1, bc = (t & 1) * 32;   // B: 128 rows x 64 cols, 4 uint4/thr
    const _Float16* gA = A + (size_t)(m0 + ar) * K + ac;
    const _Float16* gW = W + (size_t)(n0 + br) * K + bc;

    uint4 ra0 = *reinterpret_cast<const uint4*>(gA);
    uint4 ra1 = *reinterpret_cast<const uint4*>(gA + 8);
    uint4 rb0 = *reinterpret_cast<const uint4*>(gW);
    uint4 rb1 = *reinterpret_cast<const uint4*>(gW + 8);
    uint4 rb2 = *reinterpret_cast<const uint4*>(gW + 16);
    uint4 rb3 = *reinterpret_cast<const uint4*>(gW + 24);

    f32x4 acc[2][4];
    #pragma unroll
    for (int i = 0; i < 2; ++i)
        #pragma unroll
        for (int j = 0; j < 4; ++j) acc[i][j] = (f32x4){0.f, 0.f, 0.f, 0.f};

    for (int k0 = 0; k0 < K; k0 += 64) {
        __syncthreads();                      // prior frag reads done
        *reinterpret_cast<uint4*>(&As[ar][ac])      = ra0;
        *reinterpret_cast<uint4*>(&As[ar][ac + 8])  = ra1;
        *reinterpret_cast<uint4*>(&Bs[br][bc])      = rb0;
        *reinterpret_cast<uint4*>(&Bs[br][bc + 8])  = rb1;
        *reinterpret_cast<uint4*>(&Bs[br][bc + 16]) = rb2;
        *reinterpret_cast<uint4*>(&Bs[br][bc + 24]) = rb3;
        if (k0 + 64 < K) {                    // prefetch next K-tile into regs
            ra0 = *reinterpret_cast<const uint4*>(gA + k0 + 64);
            ra1 = *reinterpret_cast<const uint4*>(gA + k0 + 72);
            rb0 = *reinterpret_cast<const uint4*>(gW + k0 + 64);
            rb1 = *reinterpret_cast<const uint4*>(gW + k0 + 72);
            rb2 = *reinterpret_cast<const uint4*>(gW + k0 + 80);
            rb3 = *reinterpret_cast<const uint4*>(gW + k0 + 88);
        }
        __syncthreads();                      // LDS writes visible

        #pragma unroll
        for (int ks = 0; ks < 64; ks += 32) {
            f16x8 af[2], bf[4];
            #pragma unroll
            for (int i = 0; i < 2; ++i)
                af[i] = *reinterpret_cast<const f16x8*>(&As[wm + i * 16 + l][ks + q * 8]);
            #pragma unroll
            for (int j = 0; j < 4; ++j)
                bf[j] = *reinterpret_cast<const f16x8*>(&Bs[wn + j * 16 + l][ks + q * 8]);
            #pragma unroll
            for (int i = 0; i < 2; ++i)
                #pragma unroll
                for (int j = 0; j < 4; ++j)
                    acc[i][j] = MFMA16(af[i], bf[j], acc[i][j]);
        }
    }

    // epilogue: C/D layout row = q*4 + r, col = l (per 16x16 tile)
    #pragma unroll
    for (int i = 0; i < 2; ++i) {
        #pragma unroll
        for (int j = 0; j < 4; ++j) {
            int gnb = n0 + wn + j * 16 + l;
            float bc2 = BIAS_ROW ? 0.f : bias[gnb - nbase];
            #pragma unroll
            for (int r = 0; r < 4; ++r) {
                int gm = m0 + wm + i * 16 + q * 4 + r;
                float bb = BIAS_ROW ? bias[gm] : bc2;
                C[(size_t)gm * N + gnb] = (OUT_T)((acc[i][j][r] + bb) * scale);
            }
        }
    }
}

// ---------------------------------------------------------------------------
// MFMA flash attention (causal), FIXED-MAX softmax.  Q pre-scaled by
// 0.125*log2(e): p = exp2(S' - 4); fixed shift cancels in p/sum(p).
//
// R4 post-mortem: BQ=128 halved LDS traffic (conflict ctr -43%) but occupancy
// collapsed to 12% (512 coarse blocks, tail imbalance) and __syncthreads'
// vmcnt(0) drain exposed full prefetch latency every iter -> 83us.
//
// R5 structure:
//  * BQ=128, 8 waves/block: waves 0-3 = kv lower half, waves 4-7 = upper
//    half. Both halves run exactly qt+1 iters -> symmetric barriers, and
//    every block is internally balanced. Fixed-max softmax => halves are
//    directly addable; combined in-block via LDS at the epilogue.
//  * Counted barriers (T3/T4 minimum): barrier A raw s_barrier (prev reads
//    complete via MFMA data-deps); barrier B s_waitcnt lgkmcnt(0) +
//    s_barrier. NO vmcnt drain: prefetch global loads stay in flight across
//    barriers; consumed by next iter's ds_write (compiler-inserted vmcnt).
//  * Safety: each wave reads Q/P only from its own 32 rows (same-wave DS
//    in-order); half-B aq reads drain at its own barrier-B lgkmcnt(0)
//    before half-A's first P write (post-barrier-B). Epilogue exchange
//    buffer overlays half-B LDS, guarded by two full __syncthreads.
//  * LDS 72 KB -> 2 blocks/CU, 16 waves/CU; __launch_bounds__(512,4)
//    caps VGPR at 128 so 16 waves fit.
// ---------------------------------------------------------------------------
#define APAD 72

__global__ __launch_bounds__(512, 4) void attn_mfma(
    const _Float16* __restrict__ Qg,  // [SEQ][LDQK] cols 0..1023 (pre-scaled)
    const _Float16* __restrict__ Kg,  // [SEQ][LDQK] (base already +1024)
    const _Float16* __restrict__ Vt,  // [DM][SEQ]
    _Float16* __restrict__ O)         // [SEQ][DM]
{
    // carve LDS: QPa 0..18432 | Pb ..36864 | KsB ..46080 | VsB ..55296 |
    //            KsA ..64512 | VsA ..73728   (half-B group contiguous so the
    // epilogue f32 exchange buffer (33792+512 B) overlays Pb+KsB+VsB).
    __shared__ __align__(16) char smem[73728];
    _Float16 (*QPa)[APAD]     = reinterpret_cast<_Float16(*)[APAD]>(smem);
    _Float16 (*Pb)[APAD]      = reinterpret_cast<_Float16(*)[APAD]>(smem + 18432);
    _Float16 (*KsB)[16][APAD] = reinterpret_cast<_Float16(*)[16][APAD]>(smem + 36864);
    _Float16 (*VsB)[APAD]     = reinterpret_cast<_Float16(*)[APAD]>(smem + 46080);
    _Float16 (*KsA)[16][APAD] = reinterpret_cast<_Float16(*)[16][APAD]>(smem + 55296);
    _Float16 (*VsA)[APAD]     = reinterpret_cast<_Float16(*)[APAD]>(smem + 64512);

    const int t    = threadIdx.x;          // 0..511
    const int h    = blockIdx.x;
    const int by   = blockIdx.y;           // 0..31
    const int qt   = (by < 16) ? by : 47 - by;   // q-tile 0..31 (pair-balanced)
    const int hb   = t >> 8;               // 0 = kv half A, 1 = half B
    const int sub  = (t >> 6) & 3;         // wave within half
    const int lane = t & 63;
    const int q    = lane >> 4;
    const int l    = lane & 15;
    const int tt   = t & 255;
    const int sr   = tt >> 3;              // 0..31 staging row
    const int sc   = (tt & 7) * 8;         // staging col (f16)
    const int kj   = sr & 3;               // K group for rows sr / sr+32
    const int kn   = sr >> 2;

    _Float16 (*Ks)[16][APAD] = hb ? KsB : KsA;
    _Float16 (*Vs)[APAD]     = hb ? VsB : VsA;
    _Float16 (*Pp)[APAD]     = hb ? Pb  : QPa;

    // ---- stage Q: 128 rows x 64 cols, 1 row / thread ----
    const int qsr = t >> 2, qsc = (t & 3) * 16;
    *reinterpret_cast<uint4*>(&QPa[qsr][qsc]) =
        *reinterpret_cast<const uint4*>(Qg + (size_t)(qt * 128 + qsr) * LDQK + h * 64 + qsc);
    *reinterpret_cast<uint4*>(&QPa[qsr][qsc + 8]) =
        *reinterpret_cast<const uint4*>(Qg + (size_t)(qt * 128 + qsr) * LDQK + h * 64 + qsc + 8);

    // ---- prefetch this half's first K/V tile into registers ----
    const int kt0 = hb ? (qt + 1) : 0;
    uint4 kr0 = *reinterpret_cast<const uint4*>(Kg + (size_t)(kt0 * 64 + sr) * LDQK + h * 64 + sc);
    uint4 kr1 = *reinterpret_cast<const uint4*>(Kg + (size_t)(kt0 * 64 + sr + 32) * LDQK + h * 64 + sc);
    uint4 vr0 = *reinterpret_cast<const uint4*>(Vt + (size_t)(h * 64 + sr) * SEQ + kt0 * 64 + sc);
    uint4 vr1 = *reinterpret_cast<const uint4*>(Vt + (size_t)(h * 64 + sr + 32) * SEQ + kt0 * 64 + sc);

    float l_acc[2][4];
    f32x4 oacc[2][4];
    #pragma unroll
    for (int i = 0; i < 2; ++i)
        #pragma unroll
        for (int nt = 0; nt < 4; ++nt) {
            oacc[i][nt] = (f32x4){0.f, 0.f, 0.f, 0.f};
            l_acc[i][nt] = 0.f;
        }

    asm volatile("s_waitcnt lgkmcnt(0)" ::: "memory");
    __builtin_amdgcn_s_barrier();          // Q visible to all waves
    __builtin_amdgcn_sched_barrier(0);

    // wave's 32 q-rows: [sub*32, sub*32+32)
    f16x8 aq[2][2];
    #pragma unroll
    for (int i = 0; i < 2; ++i) {
        aq[i][0] = *reinterpret_cast<const f16x8*>(&QPa[sub * 32 + i * 16 + l][q * 8]);
        aq[i][1] = *reinterpret_cast<const f16x8*>(&QPa[sub * 32 + i * 16 + l][32 + q * 8]);
    }
    // aq reads drain at this wave's next lgkmcnt(0); half-A P writes to these
    // rows only occur after barrier B below -> no cross-wave race.

    for (int it = 0; it <= qt; ++it) {
        const int kt = kt0 + it;

        __builtin_amdgcn_sched_barrier(0);
        __builtin_amdgcn_s_barrier();      // A: prev iter reads done (data-dep)
        __builtin_amdgcn_sched_barrier(0);

        *reinterpret_cast<uint4*>(&Ks[kj][kn][sc])     = kr0;   // vmcnt auto-wait
        *reinterpret_cast<uint4*>(&Ks[kj][kn + 8][sc]) = kr1;
        *reinterpret_cast<uint4*>(&Vs[sr][sc])         = vr0;
        *reinterpret_cast<uint4*>(&Vs[sr + 32][sc])    = vr1;
        if (it < qt) {                     // issue next-tile loads (stay in flight)
            kr0 = *reinterpret_cast<const uint4*>(
                Kg + (size_t)((kt + 1) * 64 + sr) * LDQK + h * 64 + sc);
            kr1 = *reinterpret_cast<const uint4*>(
                Kg + (size_t)((kt + 1) * 64 + sr + 32) * LDQK + h * 64 + sc);
            vr0 = *reinterpret_cast<const uint4*>(
                Vt + (size_t)(h * 64 + sr) * SEQ + (kt + 1) * 64 + sc);
            vr1 = *reinterpret_cast<const uint4*>(
                Vt + (size_t)(h * 64 + sr + 32) * SEQ + (kt + 1) * 64 + sc);
        }
        asm volatile("s_waitcnt lgkmcnt(0)" ::: "memory");
        __builtin_amdgcn_s_barrier();      // B: LDS writes visible (no vmcnt drain)
        __builtin_amdgcn_sched_barrier(0);

        // ---- S' = Q @ K^T; tile jt <- K rows {4n+jt} = Ks[jt][n] ----
        f32x4 s0[4], s1[4];
        __builtin_amdgcn_s_setprio(1);
        #pragma unroll
        for (int jt = 0; jt < 4; ++jt) {
            f16x8 bk0 = *reinterpret_cast<const f16x8*>(&Ks[jt][l][q * 8]);
            f16x8 bk1 = *reinterpret_cast<const f16x8*>(&Ks[jt][l][32 + q * 8]);
            f32x4 z0 = (f32x4){0.f, 0.f, 0.f, 0.f};
            z0 = MFMA16(aq[0][0], bk0, z0);
            z0 = MFMA16(aq[0][1], bk1, z0);
            s0[jt] = z0;
            f32x4 z1 = (f32x4){0.f, 0.f, 0.f, 0.f};
            z1 = MFMA16(aq[1][0], bk0, z1);
            z1 = MFMA16(aq[1][1], bk1, z1);
            s1[jt] = z1;
        }
        __builtin_amdgcn_s_setprio(0);

        const bool need_mask = (kt >= 2 * qt);

        // ---- p = exp2(S' - 4); accumulate per-lane l; stage P ----
        #pragma unroll
        for (int i = 0; i < 2; ++i) {
            #pragma unroll
            for (int r = 0; r < 4; ++r) {
                float p0 = (i ? s1 : s0)[0][r], p1 = (i ? s1 : s0)[1][r];
                float p2 = (i ? s1 : s0)[2][r], p3 = (i ? s1 : s0)[3][r];
                if (need_mask) {
                    const int qg = qt * 128 + sub * 32 + i * 16 + q * 4 + r;
                    const int kg = kt * 64 + 4 * l;
                    p0 = (kg + 0 <= qg) ? p0 : -1e30f;
                    p1 = (kg + 1 <= qg) ? p1 : -1e30f;
                    p2 = (kg + 2 <= qg) ? p2 : -1e30f;
                    p3 = (kg + 3 <= qg) ? p3 : -1e30f;
                }
                p0 = __builtin_amdgcn_exp2f(p0 - 4.f);
                p1 = __builtin_amdgcn_exp2f(p1 - 4.f);
                p2 = __builtin_amdgcn_exp2f(p2 - 4.f);
                p3 = __builtin_amdgcn_exp2f(p3 - 4.f);
                l_acc[i][r] += (p0 + p1) + (p2 + p3);
                f16x4 pk = {(_Float16)p0, (_Float16)p1, (_Float16)p2, (_Float16)p3};
                *reinterpret_cast<f16x4*>(&Pp[sub * 32 + i * 16 + q * 4 + r][4 * l]) = pk;
            }
        }
        // no barrier: P rows wave-private; same-wave ds ops are in-order.

        // ---- O += P @ V ----
        f16x8 ap[2][2];
        #pragma unroll
        for (int i = 0; i < 2; ++i) {
            ap[i][0] = *reinterpret_cast<const f16x8*>(&Pp[sub * 32 + i * 16 + l][q * 8]);
            ap[i][1] = *reinterpret_cast<const f16x8*>(&Pp[sub * 32 + i * 16 + l][32 + q * 8]);
        }
        __builtin_amdgcn_s_setprio(1);
        #pragma unroll
        for (int nt = 0; nt < 4; ++nt) {
            f16x8 bv0 = *reinterpret_cast<const f16x8*>(&Vs[nt * 16 + l][q * 8]);
            f16x8 bv1 = *reinterpret_cast<const f16x8*>(&Vs[nt * 16 + l][32 + q * 8]);
            oacc[0][nt] = MFMA16(ap[0][0], bv0, oacc[0][nt]);
            oacc[0][nt] = MFMA16(ap[0][1], bv1, oacc[0][nt]);
            oacc[1][nt] = MFMA16(ap[1][0], bv0, oacc[1][nt]);
            oacc[1][nt] = MFMA16(ap[1][1], bv1, oacc[1][nt]);
        }
        __builtin_amdgcn_s_setprio(0);
    }

    // ---- combine halves in-block, normalize, store ----
    float* Xf = reinterpret_cast<float*>(smem + 18432);   // [128][66] f32
    float* Xl = reinterpret_cast<float*>(smem + 52224);   // [128] f32

    __syncthreads();   // all kv-loop LDS reads done before overlay writes
    if (hb) {
        #pragma unroll
        for (int i = 0; i < 2; ++i) {
            #pragma unroll
            for (int r = 0; r < 4; ++r) {
                float lb = red16_add(l_acc[i][r]);
                int row = sub * 32 + i * 16 + q * 4 + r;
                if (l == 0) Xl[row] = lb;
                #pragma unroll
                for (int nt = 0; nt < 4; ++nt)
                    Xf[row * 66 + nt * 16 + l] = oacc[i][nt][r];
            }
        }
    }
    __syncthreads();   // half-B partials visible
    if (!hb) {
        #pragma unroll
        for (int i = 0; i < 2; ++i) {
            #pragma unroll
            for (int r = 0; r < 4; ++r) {
                int row = sub * 32 + i * 16 + q * 4 + r;
                float lsum = red16_add(l_acc[i][r]) + Xl[row];
                float inv = 1.f / lsum;
                size_t grow = (size_t)(qt * 128 + row) * DM + h * 64;
                #pragma unroll
                for (int nt = 0; nt < 4; ++nt)
                    O[grow + nt * 16 + l] =
                        (_Float16)((oacc[i][nt][r] + Xf[row * 66 + nt * 16 + l]) * inv);
            }
        }
    }
}

// ---------------------------------------------------------------------------
extern "C" void kernel_launch(void* const* d_in, const int* in_sizes, int n_in,
                              void* d_out, int out_size, void* d_ws, size_t ws_size,
                              hipStream_t stream)
{
    const float* x  = (const float*)d_in[0];
    const float* wq = (const float*)d_in[1];
    const float* bq = (const float*)d_in[2];
    const float* wk = (const float*)d_in[3];
    const float* bk = (const float*)d_in[4];
    const float* wv = (const float*)d_in[5];
    const float* bv = (const float*)d_in[6];
    const float* wo = (const float*)d_in[7];
    const float* bo = (const float*)d_in[8];
    float* out = (float*)d_out;

    char* ws = (char*)d_ws;
    _Float16* xb   = (_Float16*)(ws);                    // 8 MB
    _Float16* wqkb = (_Float16*)(ws + (8ull  << 20));    // 4 MB [wq;wk] stacked
    _Float16* wvb  = (_Float16*)(ws + (12ull << 20));    // 2 MB
    _Float16* wob  = (_Float16*)(ws + (14ull << 20));    // 2 MB
    _Float16* QKb  = (_Float16*)(ws + (16ull << 20));    // 16 MB [SEQ][2048]: Q|K
    _Float16* Vtb  = (_Float16*)(ws + (32ull << 20));    // 8 MB V^T [DM][SEQ]
    _Float16* Ab   = (_Float16*)(ws + (40ull << 20));    // 8 MB attn out

    // one cast launch: x + all 4 weights (wq/wk stacked into wqkb)
    cast_all<<<dim3(SEQ * DM / 1024, 2), dim3(256), 0, stream>>>(
        x, wq, wk, wv, wo, xb, wqkb, wvb, wob);

    // fused Q|K projection: C[:, :1024] = (x@wq^T + bq)*0.125*log2e,
    //                       C[:, 1024:] = x@wk^T + bk
    gemm_bt_f16<0, _Float16><<<dim3(2048 / 128, SEQ / 64), dim3(256), 0, stream>>>(
        xb, wqkb, bq, bk, QKb, SEQ, 2048, DM,
        0.18033688011112042f, 1.0f, 1024);

    // Vt[dm][seq] = wv@x^T + bv (bias on rows)
    gemm_bt_f16<1, _Float16><<<dim3(SEQ / 128, DM / 64), dim3(256), 0, stream>>>(
        wvb, xb, bv, bv, Vtb, DM, SEQ, DM, 1.0f, 1.0f, 1 << 30);

    // BQ=128, 8 waves (two kv halves), 512 blocks -> 2 blocks/CU, 16 waves/CU
    attn_mfma<<<dim3(NH, 32), dim3(512), 0, stream>>>(QKb, QKb + 1024, Vtb, Ab);

    // out = attn@wo^T + bo (f32 out)
    gemm_bt_f16<0, float><<<dim3(DM / 128, SEQ / 64), dim3(256), 0, stream>>>(
        Ab, wob, bo, bo, out, SEQ, DM, DM, 1.0f, 1.0f, 1 << 30);
}

// Round 7
// 216.280 us; speedup vs baseline: 1.0938x; 1.0938x over previous
//
#include <hip/hip_runtime.h>

// Problem: B=1, S=4096, D=1024, H=16, hs=64. f32 in/out, f16 MFMA internally.
#define SEQ 4096
#define DM  1024
#define NH  16
#define HS  64
#define LDQK 2048   // Q|K stacked projection buffer row stride

typedef __attribute__((ext_vector_type(8))) _Float16 f16x8;
typedef __attribute__((ext_vector_type(4))) _Float16 f16x4;
typedef __attribute__((ext_vector_type(4))) float    f32x4;

#define MFMA16(a, b, c) __builtin_amdgcn_mfma_f32_16x16x32_f16((a), (b), (c), 0, 0, 0)

// address-space casts for global_load_lds (flat -> AS1/AS3 via addrspacecast)
#define AS1(p) ((const __attribute__((address_space(1))) void*)(p))
#define AS3(p) ((__attribute__((address_space(3))) void*)(p))

// DPP row_ror reduction across a 16-lane DPP row (epilogue only).
#define DPP_ROR_F(x, N) __int_as_float(__builtin_amdgcn_update_dpp( \
    0, __float_as_int(x), 0x120 + (N), 0xF, 0xF, false))

__device__ __forceinline__ float red16_add(float x) {
    x += DPP_ROR_F(x, 1);
    x += DPP_ROR_F(x, 2);
    x += DPP_ROR_F(x, 4);
    x += DPP_ROR_F(x, 8);
    return x;
}

// ---------------------------------------------------------------------------
// single cast launch: y=0 -> x (4M elems), y=1 -> 4 weights (1M each).
// wq/wk land stacked in wqkb[2048][1024] so Q,K project as ONE GEMM.
// ---------------------------------------------------------------------------
__global__ __launch_bounds__(256) void cast_all(
    const float* __restrict__ x,
    const float* __restrict__ wq, const float* __restrict__ wk,
    const float* __restrict__ wv, const float* __restrict__ wo,
    _Float16* __restrict__ xb, _Float16* __restrict__ wqkb,
    _Float16* __restrict__ wvb, _Float16* __restrict__ wob)
{
    const float* s; _Float16* d; int i;
    if (blockIdx.y == 0) {
        s = x; d = xb;
        i = blockIdx.x * 1024 + threadIdx.x * 4;
    } else {
        int wsel = blockIdx.x >> 10;       // 0..3
        int bx   = blockIdx.x & 1023;
        switch (wsel) {
            case 0:  s = wq; d = wqkb;               break;
            case 1:  s = wk; d = wqkb + (1u << 20);  break;  // rows 1024..2047
            case 2:  s = wv; d = wvb;                break;
            default: s = wo; d = wob;                break;
        }
        i = bx * 1024 + threadIdx.x * 4;
    }
    float4 v = *reinterpret_cast<const float4*>(s + i);
    f16x4 o = {(_Float16)v.x, (_Float16)v.y, (_Float16)v.z, (_Float16)v.w};
    *reinterpret_cast<f16x4*>(d + i) = o;
}

// ---------------------------------------------------------------------------
// m97-structure MFMA GEMM with global_load_lds staging (R6, resubmitted R7 —
// prior round was an infra failure, kernel never measured).
// C[M][N] = (A[M][K] @ W[N][K]^T + bias) * scale
// BM x 128 tile, BK=64, 256 thr / 4 waves.
//   BM=128: wave tile 64x64 (acc 4x4), grid (N/128, M/128)
//   BM=64 : wave tile 32x64 (acc 2x4), grid (N/128, M/64)
// Staging: __builtin_amdgcn_global_load_lds width=16 — LDS dest is
// wave-uniform base + lane*16, so LDS is LINEAR [BM][64] (no pad); each
// 1 KB chunk = 8 rows; lane's global src row = chunk*8 + (lane>>3),
// col = (lane&7)*8. __syncthreads() after issue drains vmcnt(0) (m97's
// known ~20% stall, still 874-912 TF measured vs 646 reg-staged).
// nsplit: column-split for fused Q|K (bias_hi/scale_hi for n0 >= nsplit).
// ---------------------------------------------------------------------------
template <int BM, int BIAS_ROW, typename OUT_T>
__global__ __launch_bounds__(256, 2) void gemm_lds(
    const _Float16* __restrict__ A,    // [M][K]
    const _Float16* __restrict__ W,    // [N][K]
    const float*    __restrict__ bias_lo,
    const float*    __restrict__ bias_hi,
    OUT_T* __restrict__ C,             // [M][N]
    int M, int N, int K,
    float scale_lo, float scale_hi, int nsplit)
{
    constexpr int MI = BM / 32;            // acc row-tiles per wave
    __shared__ _Float16 As[BM][64];        // BM/8 KB, linear
    __shared__ _Float16 Bs[128][64];       // 16 KB, linear

    const int t    = threadIdx.x;
    const int w    = t >> 6;
    const int lane = t & 63;
    const int q    = lane >> 4;
    const int l    = lane & 15;
    const int m0   = blockIdx.y * BM;
    const int n0   = blockIdx.x * 128;
    const int wm   = (w & 1) * (BM / 2);
    const int wn   = (w >> 1) * 64;

    const float* bias  = (n0 < nsplit) ? bias_lo : bias_hi;
    const int    nbase = (n0 < nsplit) ? 0 : nsplit;
    const float  scale = (n0 < nsplit) ? scale_lo : scale_hi;

    const int srow = lane >> 3;            // 0..7 row within 8-row chunk
    const int scol = (lane & 7) * 8;       // 0..56 col (f16)

    f32x4 acc[MI][4];
    #pragma unroll
    for (int i = 0; i < MI; ++i)
        #pragma unroll
        for (int j = 0; j < 4; ++j) acc[i][j] = (f32x4){0.f, 0.f, 0.f, 0.f};

    for (int k0 = 0; k0 < K; k0 += 64) {
        __syncthreads();                   // prior frag reads done
        // ---- stage A: BM/8 chunks of 1 KB, BM/32 per wave ----
        #pragma unroll
        for (int j = 0; j < BM / 32; ++j) {
            int c = w * (BM / 32) + j;
            __builtin_amdgcn_global_load_lds(
                AS1(A + (size_t)(m0 + c * 8 + srow) * K + k0 + scol),
                AS3((char*)&As[0][0] + c * 1024), 16, 0, 0);
        }
        // ---- stage B: 16 chunks, 4 per wave ----
        #pragma unroll
        for (int j = 0; j < 4; ++j) {
            int c = w * 4 + j;
            __builtin_amdgcn_global_load_lds(
                AS1(W + (size_t)(n0 + c * 8 + srow) * K + k0 + scol),
                AS3((char*)&Bs[0][0] + c * 1024), 16, 0, 0);
        }
        __syncthreads();                   // vmcnt(0) drain: tiles visible

        #pragma unroll
        for (int ks = 0; ks < 64; ks += 32) {
            f16x8 af[MI], bf[4];
            #pragma unroll
            for (int i = 0; i < MI; ++i)
                af[i] = *reinterpret_cast<const f16x8*>(&As[wm + i * 16 + l][ks + q * 8]);
            #pragma unroll
            for (int j = 0; j < 4; ++j)
                bf[j] = *reinterpret_cast<const f16x8*>(&Bs[wn + j * 16 + l][ks + q * 8]);
            #pragma unroll
            for (int i = 0; i < MI; ++i)
                #pragma unroll
                for (int j = 0; j < 4; ++j)
                    acc[i][j] = MFMA16(af[i], bf[j], acc[i][j]);
        }
    }

    // epilogue: C/D layout row = q*4 + r, col = l (per 16x16 tile)
    #pragma unroll
    for (int i = 0; i < MI; ++i) {
        #pragma unroll
        for (int j = 0; j < 4; ++j) {
            int gnb = n0 + wn + j * 16 + l;
            float bc2 = BIAS_ROW ? 0.f : bias[gnb - nbase];
            #pragma unroll
            for (int r = 0; r < 4; ++r) {
                int gm = m0 + wm + i * 16 + q * 4 + r;
                float bb = BIAS_ROW ? bias[gm] : bc2;
                C[(size_t)gm * N + gnb] = (OUT_T)((acc[i][j][r] + bb) * scale);
            }
        }
    }
}

// ---------------------------------------------------------------------------
// MFMA flash attention (causal), FIXED-MAX softmax — R3 version (measured
// 70.1 us), reverted verbatim after R4/R5 restructure regressions.
// Q pre-scaled by 0.125*log2(e): S' = S*log2e; p = exp2(S' - 4).
// 4 blocks/CU: grid (NH, 64), one 64-row q-tile per block, balanced remap
// qb = by<32 ? by : 95-by. Single-buffered K/V, 36.9 KB LDS,
// __launch_bounds__(256,4). K grouped by jt: Ks[jt][n] holds K row 4n+jt.
// ---------------------------------------------------------------------------
#define APAD 72

__global__ __launch_bounds__(256, 4) void attn_mfma(
    const _Float16* __restrict__ Qg,  // [SEQ][LDQK] cols 0..1023 (pre-scaled)
    const _Float16* __restrict__ Kg,  // [SEQ][LDQK] (base already +1024)
    const _Float16* __restrict__ Vt,  // [DM][SEQ]
    _Float16* __restrict__ O)         // [SEQ][DM]
{
    __shared__ _Float16 Qs[64][APAD];        // 9.2 KB
    __shared__ _Float16 Ks[4][16][APAD];     // 9.2 KB  [jt][n]: K row 4n+jt
    __shared__ _Float16 Vs[64][APAD];        // 9.2 KB
    __shared__ _Float16 Ps[64][APAD];        // 9.2 KB   (total 36.9 KB -> 4/CU)

    const int t    = threadIdx.x;
    const int h    = blockIdx.x;
    const int by   = blockIdx.y;      // 0..63
    const int qb   = (by < 32) ? by : 95 - by;   // balanced q-tile index
    const int w    = t >> 6;          // wave 0..3
    const int lane = t & 63;
    const int q    = lane >> 4;
    const int l    = lane & 15;
    const int sr   = t >> 3;          // 0..31 staging row
    const int sc   = (t & 7) * 8;     // staging col (f16)
    const int kj   = sr & 3;          // K physical group for row sr / sr+32
    const int kn   = sr >> 2;

    // stage Q
    *reinterpret_cast<uint4*>(&Qs[sr][sc]) =
        *reinterpret_cast<const uint4*>(Qg + (size_t)(qb * 64 + sr) * LDQK + h * 64 + sc);
    *reinterpret_cast<uint4*>(&Qs[sr + 32][sc]) =
        *reinterpret_cast<const uint4*>(Qg + (size_t)(qb * 64 + sr + 32) * LDQK + h * 64 + sc);

    // prefetch kt=0 K/V into registers
    uint4 kr0 = *reinterpret_cast<const uint4*>(Kg + (size_t)(sr) * LDQK + h * 64 + sc);
    uint4 kr1 = *reinterpret_cast<const uint4*>(Kg + (size_t)(sr + 32) * LDQK + h * 64 + sc);
    uint4 vr0 = *reinterpret_cast<const uint4*>(Vt + (size_t)(h * 64 + sr) * SEQ + sc);
    uint4 vr1 = *reinterpret_cast<const uint4*>(Vt + (size_t)(h * 64 + sr + 32) * SEQ + sc);

    float l_acc[4] = {0.f, 0.f, 0.f, 0.f};
    f32x4 oacc[4];
    #pragma unroll
    for (int nt = 0; nt < 4; ++nt) oacc[nt] = (f32x4){0.f, 0.f, 0.f, 0.f};

    __syncthreads();   // Qs visible
    f16x8 aq0 = *reinterpret_cast<const f16x8*>(&Qs[w * 16 + l][q * 8]);
    f16x8 aq1 = *reinterpret_cast<const f16x8*>(&Qs[w * 16 + l][32 + q * 8]);

    const int qrow_base = qb * 64 + w * 16 + q * 4;   // + r = global q row

    for (int kt = 0; kt <= qb; ++kt) {
        __syncthreads();   // prev iter's Ks/Vs reads done
        *reinterpret_cast<uint4*>(&Ks[kj][kn][sc])     = kr0;
        *reinterpret_cast<uint4*>(&Ks[kj][kn + 8][sc]) = kr1;
        *reinterpret_cast<uint4*>(&Vs[sr][sc])         = vr0;
        *reinterpret_cast<uint4*>(&Vs[sr + 32][sc])    = vr1;
        if (kt < qb) {   // issue kt+1 global loads
            kr0 = *reinterpret_cast<const uint4*>(
                Kg + (size_t)((kt + 1) * 64 + sr) * LDQK + h * 64 + sc);
            kr1 = *reinterpret_cast<const uint4*>(
                Kg + (size_t)((kt + 1) * 64 + sr + 32) * LDQK + h * 64 + sc);
            vr0 = *reinterpret_cast<const uint4*>(
                Vt + (size_t)(h * 64 + sr) * SEQ + (kt + 1) * 64 + sc);
            vr1 = *reinterpret_cast<const uint4*>(
                Vt + (size_t)(h * 64 + sr + 32) * SEQ + (kt + 1) * 64 + sc);
        }
        __syncthreads();   // LDS writes visible

        // ---- S' = Q @ K^T; tile jt <- K rows {4n+jt} = Ks[jt][n] ----
        f32x4 s[4];
        __builtin_amdgcn_s_setprio(1);
        #pragma unroll
        for (int jt = 0; jt < 4; ++jt) {
            f16x8 bk0 = *reinterpret_cast<const f16x8*>(&Ks[jt][l][q * 8]);
            f16x8 bk1 = *reinterpret_cast<const f16x8*>(&Ks[jt][l][32 + q * 8]);
            f32x4 z = (f32x4){0.f, 0.f, 0.f, 0.f};
            z = MFMA16(aq0, bk0, z);
            z = MFMA16(aq1, bk1, z);
            s[jt] = z;   // s[jt][r] = S'[qrow_base+r][kt*64 + 4l + jt]
        }
        __builtin_amdgcn_s_setprio(0);

        const bool diag = (kt == qb);

        // ---- p = exp2(S' - 4); accumulate per-lane l; stage P ----
        #pragma unroll
        for (int r = 0; r < 4; ++r) {
            float p0 = s[0][r], p1 = s[1][r], p2 = s[2][r], p3 = s[3][r];
            if (diag) {
                const int qg = qrow_base + r;
                const int kg = kt * 64 + 4 * l;
                p0 = (kg + 0 <= qg) ? p0 : -1e30f;
                p1 = (kg + 1 <= qg) ? p1 : -1e30f;
                p2 = (kg + 2 <= qg) ? p2 : -1e30f;
                p3 = (kg + 3 <= qg) ? p3 : -1e30f;
            }
            p0 = __builtin_amdgcn_exp2f(p0 - 4.f);
            p1 = __builtin_amdgcn_exp2f(p1 - 4.f);
            p2 = __builtin_amdgcn_exp2f(p2 - 4.f);
            p3 = __builtin_amdgcn_exp2f(p3 - 4.f);
            l_acc[r] += (p0 + p1) + (p2 + p3);
            f16x4 pk = {(_Float16)p0, (_Float16)p1, (_Float16)p2, (_Float16)p3};
            *reinterpret_cast<f16x4*>(&Ps[w * 16 + q * 4 + r][4 * l]) = pk;
        }
        // no barrier: Ps rows [w*16, w*16+16) wave-private;
        // same-wave ds_write -> ds_read ordered by lgkmcnt.

        // ---- O += P @ V ----
        f16x8 ap0 = *reinterpret_cast<const f16x8*>(&Ps[w * 16 + l][q * 8]);
        f16x8 ap1 = *reinterpret_cast<const f16x8*>(&Ps[w * 16 + l][32 + q * 8]);
        __builtin_amdgcn_s_setprio(1);
        #pragma unroll
        for (int nt = 0; nt < 4; ++nt) {
            f16x8 bv0 = *reinterpret_cast<const f16x8*>(&Vs[nt * 16 + l][q * 8]);
            f16x8 bv1 = *reinterpret_cast<const f16x8*>(&Vs[nt * 16 + l][32 + q * 8]);
            oacc[nt] = MFMA16(ap0, bv0, oacc[nt]);
            oacc[nt] = MFMA16(ap1, bv1, oacc[nt]);
        }
        __builtin_amdgcn_s_setprio(0);
    }

    // ---- epilogue: reduce l across the 16-lane row, normalize, store ----
    #pragma unroll
    for (int r = 0; r < 4; ++r) {
        float inv = 1.f / red16_add(l_acc[r]);
        size_t row = (size_t)(qb * 64 + w * 16 + q * 4 + r) * DM + h * 64;
        #pragma unroll
        for (int nt = 0; nt < 4; ++nt)
            O[row + nt * 16 + l] = (_Float16)(oacc[nt][r] * inv);
    }
}

// ---------------------------------------------------------------------------
extern "C" void kernel_launch(void* const* d_in, const int* in_sizes, int n_in,
                              void* d_out, int out_size, void* d_ws, size_t ws_size,
                              hipStream_t stream)
{
    const float* x  = (const float*)d_in[0];
    const float* wq = (const float*)d_in[1];
    const float* bq = (const float*)d_in[2];
    const float* wk = (const float*)d_in[3];
    const float* bk = (const float*)d_in[4];
    const float* wv = (const float*)d_in[5];
    const float* bv = (const float*)d_in[6];
    const float* wo = (const float*)d_in[7];
    const float* bo = (const float*)d_in[8];
    float* out = (float*)d_out;

    char* ws = (char*)d_ws;
    _Float16* xb   = (_Float16*)(ws);                    // 8 MB
    _Float16* wqkb = (_Float16*)(ws + (8ull  << 20));    // 4 MB [wq;wk] stacked
    _Float16* wvb  = (_Float16*)(ws + (12ull << 20));    // 2 MB
    _Float16* wob  = (_Float16*)(ws + (14ull << 20));    // 2 MB
    _Float16* QKb  = (_Float16*)(ws + (16ull << 20));    // 16 MB [SEQ][2048]: Q|K
    _Float16* Vtb  = (_Float16*)(ws + (32ull << 20));    // 8 MB V^T [DM][SEQ]
    _Float16* Ab   = (_Float16*)(ws + (40ull << 20));    // 8 MB attn out

    // one cast launch: x + all 4 weights (wq/wk stacked into wqkb)
    cast_all<<<dim3(SEQ * DM / 1024, 2), dim3(256), 0, stream>>>(
        x, wq, wk, wv, wo, xb, wqkb, wvb, wob);

    // fused Q|K projection (BM=128): C[:, :1024] = (x@wq^T + bq)*0.125*log2e,
    //                                C[:, 1024:] = x@wk^T + bk
    gemm_lds<128, 0, _Float16><<<dim3(2048 / 128, SEQ / 128), dim3(256), 0, stream>>>(
        xb, wqkb, bq, bk, QKb, SEQ, 2048, DM,
        0.18033688011112042f, 1.0f, 1024);

    // Vt[dm][seq] = wv@x^T + bv (bias on rows), BM=64 -> 512 blocks
    gemm_lds<64, 1, _Float16><<<dim3(SEQ / 128, DM / 64), dim3(256), 0, stream>>>(
        wvb, xb, bv, bv, Vtb, DM, SEQ, DM, 1.0f, 1.0f, 1 << 30);

    // attn: 1024 blocks -> 4 blocks/CU (36.9 KB LDS each)
    attn_mfma<<<dim3(NH, 64), dim3(256), 0, stream>>>(QKb, QKb + 1024, Vtb, Ab);

    // out = attn@wo^T + bo (f32 out), BM=64 -> 512 blocks
    gemm_lds<64, 0, float><<<dim3(DM / 128, SEQ / 64), dim3(256), 0, stream>>>(
        Ab, wob, bo, bo, out, SEQ, DM, DM, 1.0f, 1.0f, 1 << 30);
}

// Round 8
// 205.735 us; speedup vs baseline: 1.1499x; 1.0513x over previous
//
#include <hip/hip_runtime.h>

// Problem: B=1, S=4096, D=1024, H=16, hs=64. f32 in/out, f16 MFMA internally.
#define SEQ 4096
#define DM  1024
#define NH  16
#define HS  64
#define LDQK 2048   // Q|K stacked projection buffer row stride

typedef __attribute__((ext_vector_type(8))) _Float16 f16x8;
typedef __attribute__((ext_vector_type(4))) _Float16 f16x4;
typedef __attribute__((ext_vector_type(4))) float    f32x4;

#define MFMA16(a, b, c) __builtin_amdgcn_mfma_f32_16x16x32_f16((a), (b), (c), 0, 0, 0)

// address-space casts for global_load_lds (flat -> AS1/AS3 via addrspacecast)
#define AS1(p) ((const __attribute__((address_space(1))) void*)(p))
#define AS3(p) ((__attribute__((address_space(3))) void*)(p))

// DPP row_ror reduction across a 16-lane DPP row (epilogue only).
#define DPP_ROR_F(x, N) __int_as_float(__builtin_amdgcn_update_dpp( \
    0, __float_as_int(x), 0x120 + (N), 0xF, 0xF, false))

__device__ __forceinline__ float red16_add(float x) {
    x += DPP_ROR_F(x, 1);
    x += DPP_ROR_F(x, 2);
    x += DPP_ROR_F(x, 4);
    x += DPP_ROR_F(x, 8);
    return x;
}

// ---------------------------------------------------------------------------
// single cast launch: y=0 -> x (4M elems), y=1 -> 4 weights (1M each).
// wq/wk land stacked in wqkb[2048][1024] so Q,K project as ONE GEMM.
// ---------------------------------------------------------------------------
__global__ __launch_bounds__(256) void cast_all(
    const float* __restrict__ x,
    const float* __restrict__ wq, const float* __restrict__ wk,
    const float* __restrict__ wv, const float* __restrict__ wo,
    _Float16* __restrict__ xb, _Float16* __restrict__ wqkb,
    _Float16* __restrict__ wvb, _Float16* __restrict__ wob)
{
    const float* s; _Float16* d; int i;
    if (blockIdx.y == 0) {
        s = x; d = xb;
        i = blockIdx.x * 1024 + threadIdx.x * 4;
    } else {
        int wsel = blockIdx.x >> 10;       // 0..3
        int bx   = blockIdx.x & 1023;
        switch (wsel) {
            case 0:  s = wq; d = wqkb;               break;
            case 1:  s = wk; d = wqkb + (1u << 20);  break;  // rows 1024..2047
            case 2:  s = wv; d = wvb;                break;
            default: s = wo; d = wob;                break;
        }
        i = bx * 1024 + threadIdx.x * 4;
    }
    float4 v = *reinterpret_cast<const float4*>(s + i);
    f16x4 o = {(_Float16)v.x, (_Float16)v.y, (_Float16)v.z, (_Float16)v.w};
    *reinterpret_cast<f16x4*>(d + i) = o;
}

// ---------------------------------------------------------------------------
// R8 GEMM: gload_lds + LDS DOUBLE-BUFFER + XOR swizzle (T3 min-2-phase).
// C[M][N] = (A[M][K] @ W[N][K]^T + bias) * scale
// BM x 128 tile, BK=64, 256 thr / 4 waves.
//
// R7 post-mortem: single-buffered gload_lds was neutral vs reg-staged —
// (a) linear [BM][64] LDS has 128B row stride -> bank depends on col slot
//     only -> frag reads ran at 2x the b128 structural floor;
// (b) loads issued ~0cy before the vmcnt(0) drain -> ~700-900cy exposed
//     per K-iter (m102: m97-structure collapses at 2048-class sizes).
//
// Fixes:
//  * dbuf: stage(k+1) issued right AFTER the single per-iter barrier,
//    compute tile k underneath; barrier's implicit vmcnt(0) then waits on
//    loads that have had a full compute phase to fly. One tile in flight.
//    Hazard: stage(k+1) overwrites buf read in iter k-1; those reads
//    precede this iter's barrier. DMA writes occur after issue (post-
//    barrier). Reads of buf[p] this iter vs its overwrite next iter are
//    separated by next iter's barrier.
//  * XOR swizzle both sides (G4/rule#21): LDS[row][s] = G[row][s^(row&7)].
//    Write: global col16B-slot = (lane&7)^(lane>>3) (lds dest stays linear,
//    lane*16). Read: phys slot = ((ks>>3)+q)^(l&7); row&7 == l&7 for all
//    frag rows (wm, i*16 are multiples of 8). 8 slots x 8 lanes(2 rows) ->
//    disjoint 4-bank groups per cycle -> b128 floor.
// ---------------------------------------------------------------------------
template <int BM, int BIAS_ROW, typename OUT_T>
__global__ __launch_bounds__(256, 2) void gemm_lds(
    const _Float16* __restrict__ A,    // [M][K]
    const _Float16* __restrict__ W,    // [N][K]
    const float*    __restrict__ bias_lo,
    const float*    __restrict__ bias_hi,
    OUT_T* __restrict__ C,             // [M][N]
    int M, int N, int K,
    float scale_lo, float scale_hi, int nsplit)
{
    constexpr int MI = BM / 32;            // acc row-tiles per wave
    __shared__ _Float16 As[2][BM][64];     // 2 x BM/8 KB, linear+swizzled
    __shared__ _Float16 Bs[2][128][64];    // 2 x 16 KB

    const int t    = threadIdx.x;
    const int w    = t >> 6;
    const int lane = t & 63;
    const int q    = lane >> 4;
    const int l    = lane & 15;
    const int m0   = blockIdx.y * BM;
    const int n0   = blockIdx.x * 128;
    const int wm   = (w & 1) * (BM / 2);
    const int wn   = (w >> 1) * 64;

    const float* bias  = (n0 < nsplit) ? bias_lo : bias_hi;
    const int    nbase = (n0 < nsplit) ? 0 : nsplit;
    const float  scale = (n0 < nsplit) ? scale_lo : scale_hi;

    const int srow = lane >> 3;                        // 0..7 row in chunk
    const int scol = ((lane & 7) ^ (lane >> 3)) * 8;   // pre-swizzled col (f16)

    auto stage = [&](int p, int k0) {
        #pragma unroll
        for (int j = 0; j < BM / 32; ++j) {
            int c = w * (BM / 32) + j;
            __builtin_amdgcn_global_load_lds(
                AS1(A + (size_t)(m0 + c * 8 + srow) * K + k0 + scol),
                AS3((char*)&As[p][0][0] + c * 1024), 16, 0, 0);
        }
        #pragma unroll
        for (int j = 0; j < 4; ++j) {
            int c = w * 4 + j;
            __builtin_amdgcn_global_load_lds(
                AS1(W + (size_t)(n0 + c * 8 + srow) * K + k0 + scol),
                AS3((char*)&Bs[p][0][0] + c * 1024), 16, 0, 0);
        }
    };

    f32x4 acc[MI][4];
    #pragma unroll
    for (int i = 0; i < MI; ++i)
        #pragma unroll
        for (int j = 0; j < 4; ++j) acc[i][j] = (f32x4){0.f, 0.f, 0.f, 0.f};

    stage(0, 0);                           // prologue: tile 0 in flight
    int p = 0;
    for (int k0 = 0; k0 < K; k0 += 64) {
        __syncthreads();                   // vmcnt(0): tile k landed; prev-iter
                                           // reads of buf[p^1] complete
        if (k0 + 64 < K) stage(p ^ 1, k0 + 64);   // next tile flies under compute

        #pragma unroll
        for (int ks = 0; ks < 64; ks += 32) {
            f16x8 af[MI], bf[4];
            #pragma unroll
            for (int i = 0; i < MI; ++i) {
                int r = wm + i * 16 + l;
                af[i] = *reinterpret_cast<const f16x8*>(
                    (const char*)&As[p][0][0] + r * 128 +
                    ((((ks >> 3) + q) ^ (l & 7)) << 4));
            }
            #pragma unroll
            for (int j = 0; j < 4; ++j) {
                int r = wn + j * 16 + l;
                bf[j] = *reinterpret_cast<const f16x8*>(
                    (const char*)&Bs[p][0][0] + r * 128 +
                    ((((ks >> 3) + q) ^ (l & 7)) << 4));
            }
            #pragma unroll
            for (int i = 0; i < MI; ++i)
                #pragma unroll
                for (int j = 0; j < 4; ++j)
                    acc[i][j] = MFMA16(af[i], bf[j], acc[i][j]);
        }
        p ^= 1;
    }

    // epilogue: C/D layout row = q*4 + r, col = l (per 16x16 tile)
    #pragma unroll
    for (int i = 0; i < MI; ++i) {
        #pragma unroll
        for (int j = 0; j < 4; ++j) {
            int gnb = n0 + wn + j * 16 + l;
            float bc2 = BIAS_ROW ? 0.f : bias[gnb - nbase];
            #pragma unroll
            for (int r = 0; r < 4; ++r) {
                int gm = m0 + wm + i * 16 + q * 4 + r;
                float bb = BIAS_ROW ? bias[gm] : bc2;
                C[(size_t)gm * N + gnb] = (OUT_T)((acc[i][j][r] + bb) * scale);
            }
        }
    }
}

// ---------------------------------------------------------------------------
// MFMA flash attention (causal), FIXED-MAX softmax — R3 version (measured
// 70.1-70.8 us, stable across three rounds). Unchanged.
// Q pre-scaled by 0.125*log2(e): S' = S*log2e; p = exp2(S' - 4).
// 4 blocks/CU: grid (NH, 64), balanced remap qb = by<32 ? by : 95-by.
// Single-buffered K/V, 36.9 KB LDS, __launch_bounds__(256,4).
// K grouped by jt: Ks[jt][n] holds K row 4n+jt (conflict-free QK read).
// ---------------------------------------------------------------------------
#define APAD 72

__global__ __launch_bounds__(256, 4) void attn_mfma(
    const _Float16* __restrict__ Qg,  // [SEQ][LDQK] cols 0..1023 (pre-scaled)
    const _Float16* __restrict__ Kg,  // [SEQ][LDQK] (base already +1024)
    const _Float16* __restrict__ Vt,  // [DM][SEQ]
    _Float16* __restrict__ O)         // [SEQ][DM]
{
    __shared__ _Float16 Qs[64][APAD];        // 9.2 KB
    __shared__ _Float16 Ks[4][16][APAD];     // 9.2 KB  [jt][n]: K row 4n+jt
    __shared__ _Float16 Vs[64][APAD];        // 9.2 KB
    __shared__ _Float16 Ps[64][APAD];        // 9.2 KB   (total 36.9 KB -> 4/CU)

    const int t    = threadIdx.x;
    const int h    = blockIdx.x;
    const int by   = blockIdx.y;      // 0..63
    const int qb   = (by < 32) ? by : 95 - by;   // balanced q-tile index
    const int w    = t >> 6;          // wave 0..3
    const int lane = t & 63;
    const int q    = lane >> 4;
    const int l    = lane & 15;
    const int sr   = t >> 3;          // 0..31 staging row
    const int sc   = (t & 7) * 8;     // staging col (f16)
    const int kj   = sr & 3;          // K physical group for row sr / sr+32
    const int kn   = sr >> 2;

    // stage Q
    *reinterpret_cast<uint4*>(&Qs[sr][sc]) =
        *reinterpret_cast<const uint4*>(Qg + (size_t)(qb * 64 + sr) * LDQK + h * 64 + sc);
    *reinterpret_cast<uint4*>(&Qs[sr + 32][sc]) =
        *reinterpret_cast<const uint4*>(Qg + (size_t)(qb * 64 + sr + 32) * LDQK + h * 64 + sc);

    // prefetch kt=0 K/V into registers
    uint4 kr0 = *reinterpret_cast<const uint4*>(Kg + (size_t)(sr) * LDQK + h * 64 + sc);
    uint4 kr1 = *reinterpret_cast<const uint4*>(Kg + (size_t)(sr + 32) * LDQK + h * 64 + sc);
    uint4 vr0 = *reinterpret_cast<const uint4*>(Vt + (size_t)(h * 64 + sr) * SEQ + sc);
    uint4 vr1 = *reinterpret_cast<const uint4*>(Vt + (size_t)(h * 64 + sr + 32) * SEQ + sc);

    float l_acc[4] = {0.f, 0.f, 0.f, 0.f};
    f32x4 oacc[4];
    #pragma unroll
    for (int nt = 0; nt < 4; ++nt) oacc[nt] = (f32x4){0.f, 0.f, 0.f, 0.f};

    __syncthreads();   // Qs visible
    f16x8 aq0 = *reinterpret_cast<const f16x8*>(&Qs[w * 16 + l][q * 8]);
    f16x8 aq1 = *reinterpret_cast<const f16x8*>(&Qs[w * 16 + l][32 + q * 8]);

    const int qrow_base = qb * 64 + w * 16 + q * 4;   // + r = global q row

    for (int kt = 0; kt <= qb; ++kt) {
        __syncthreads();   // prev iter's Ks/Vs reads done
        *reinterpret_cast<uint4*>(&Ks[kj][kn][sc])     = kr0;
        *reinterpret_cast<uint4*>(&Ks[kj][kn + 8][sc]) = kr1;
        *reinterpret_cast<uint4*>(&Vs[sr][sc])         = vr0;
        *reinterpret_cast<uint4*>(&Vs[sr + 32][sc])    = vr1;
        if (kt < qb) {   // issue kt+1 global loads
            kr0 = *reinterpret_cast<const uint4*>(
                Kg + (size_t)((kt + 1) * 64 + sr) * LDQK + h * 64 + sc);
            kr1 = *reinterpret_cast<const uint4*>(
                Kg + (size_t)((kt + 1) * 64 + sr + 32) * LDQK + h * 64 + sc);
            vr0 = *reinterpret_cast<const uint4*>(
                Vt + (size_t)(h * 64 + sr) * SEQ + (kt + 1) * 64 + sc);
            vr1 = *reinterpret_cast<const uint4*>(
                Vt + (size_t)(h * 64 + sr + 32) * SEQ + (kt + 1) * 64 + sc);
        }
        __syncthreads();   // LDS writes visible

        // ---- S' = Q @ K^T; tile jt <- K rows {4n+jt} = Ks[jt][n] ----
        f32x4 s[4];
        __builtin_amdgcn_s_setprio(1);
        #pragma unroll
        for (int jt = 0; jt < 4; ++jt) {
            f16x8 bk0 = *reinterpret_cast<const f16x8*>(&Ks[jt][l][q * 8]);
            f16x8 bk1 = *reinterpret_cast<const f16x8*>(&Ks[jt][l][32 + q * 8]);
            f32x4 z = (f32x4){0.f, 0.f, 0.f, 0.f};
            z = MFMA16(aq0, bk0, z);
            z = MFMA16(aq1, bk1, z);
            s[jt] = z;   // s[jt][r] = S'[qrow_base+r][kt*64 + 4l + jt]
        }
        __builtin_amdgcn_s_setprio(0);

        const bool diag = (kt == qb);

        // ---- p = exp2(S' - 4); accumulate per-lane l; stage P ----
        #pragma unroll
        for (int r = 0; r < 4; ++r) {
            float p0 = s[0][r], p1 = s[1][r], p2 = s[2][r], p3 = s[3][r];
            if (diag) {
                const int qg = qrow_base + r;
                const int kg = kt * 64 + 4 * l;
                p0 = (kg + 0 <= qg) ? p0 : -1e30f;
                p1 = (kg + 1 <= qg) ? p1 : -1e30f;
                p2 = (kg + 2 <= qg) ? p2 : -1e30f;
                p3 = (kg + 3 <= qg) ? p3 : -1e30f;
            }
            p0 = __builtin_amdgcn_exp2f(p0 - 4.f);
            p1 = __builtin_amdgcn_exp2f(p1 - 4.f);
            p2 = __builtin_amdgcn_exp2f(p2 - 4.f);
            p3 = __builtin_amdgcn_exp2f(p3 - 4.f);
            l_acc[r] += (p0 + p1) + (p2 + p3);
            f16x4 pk = {(_Float16)p0, (_Float16)p1, (_Float16)p2, (_Float16)p3};
            *reinterpret_cast<f16x4*>(&Ps[w * 16 + q * 4 + r][4 * l]) = pk;
        }
        // no barrier: Ps rows [w*16, w*16+16) wave-private;
        // same-wave ds_write -> ds_read ordered by lgkmcnt.

        // ---- O += P @ V ----
        f16x8 ap0 = *reinterpret_cast<const f16x8*>(&Ps[w * 16 + l][q * 8]);
        f16x8 ap1 = *reinterpret_cast<const f16x8*>(&Ps[w * 16 + l][32 + q * 8]);
        __builtin_amdgcn_s_setprio(1);
        #pragma unroll
        for (int nt = 0; nt < 4; ++nt) {
            f16x8 bv0 = *reinterpret_cast<const f16x8*>(&Vs[nt * 16 + l][q * 8]);
            f16x8 bv1 = *reinterpret_cast<const f16x8*>(&Vs[nt * 16 + l][32 + q * 8]);
            oacc[nt] = MFMA16(ap0, bv0, oacc[nt]);
            oacc[nt] = MFMA16(ap1, bv1, oacc[nt]);
        }
        __builtin_amdgcn_s_setprio(0);
    }

    // ---- epilogue: reduce l across the 16-lane row, normalize, store ----
    #pragma unroll
    for (int r = 0; r < 4; ++r) {
        float inv = 1.f / red16_add(l_acc[r]);
        size_t row = (size_t)(qb * 64 + w * 16 + q * 4 + r) * DM + h * 64;
        #pragma unroll
        for (int nt = 0; nt < 4; ++nt)
            O[row + nt * 16 + l] = (_Float16)(oacc[nt][r] * inv);
    }
}

// ---------------------------------------------------------------------------
extern "C" void kernel_launch(void* const* d_in, const int* in_sizes, int n_in,
                              void* d_out, int out_size, void* d_ws, size_t ws_size,
                              hipStream_t stream)
{
    const float* x  = (const float*)d_in[0];
    const float* wq = (const float*)d_in[1];
    const float* bq = (const float*)d_in[2];
    const float* wk = (const float*)d_in[3];
    const float* bk = (const float*)d_in[4];
    const float* wv = (const float*)d_in[5];
    const float* bv = (const float*)d_in[6];
    const float* wo = (const float*)d_in[7];
    const float* bo = (const float*)d_in[8];
    float* out = (float*)d_out;

    char* ws = (char*)d_ws;
    _Float16* xb   = (_Float16*)(ws);                    // 8 MB
    _Float16* wqkb = (_Float16*)(ws + (8ull  << 20));    // 4 MB [wq;wk] stacked
    _Float16* wvb  = (_Float16*)(ws + (12ull << 20));    // 2 MB
    _Float16* wob  = (_Float16*)(ws + (14ull << 20));    // 2 MB
    _Float16* QKb  = (_Float16*)(ws + (16ull << 20));    // 16 MB [SEQ][2048]: Q|K
    _Float16* Vtb  = (_Float16*)(ws + (32ull << 20));    // 8 MB V^T [DM][SEQ]
    _Float16* Ab   = (_Float16*)(ws + (40ull << 20));    // 8 MB attn out

    // one cast launch: x + all 4 weights (wq/wk stacked into wqkb)
    cast_all<<<dim3(SEQ * DM / 1024, 2), dim3(256), 0, stream>>>(
        x, wq, wk, wv, wo, xb, wqkb, wvb, wob);

    // fused Q|K projection (BM=128): C[:, :1024] = (x@wq^T + bq)*0.125*log2e,
    //                                C[:, 1024:] = x@wk^T + bk
    gemm_lds<128, 0, _Float16><<<dim3(2048 / 128, SEQ / 128), dim3(256), 0, stream>>>(
        xb, wqkb, bq, bk, QKb, SEQ, 2048, DM,
        0.18033688011112042f, 1.0f, 1024);

    // Vt[dm][seq] = wv@x^T + bv (bias on rows), BM=64 -> 512 blocks
    gemm_lds<64, 1, _Float16><<<dim3(SEQ / 128, DM / 64), dim3(256), 0, stream>>>(
        wvb, xb, bv, bv, Vtb, DM, SEQ, DM, 1.0f, 1.0f, 1 << 30);

    // attn: 1024 blocks -> 4 blocks/CU (36.9 KB LDS each)
    attn_mfma<<<dim3(NH, 64), dim3(256), 0, stream>>>(QKb, QKb + 1024, Vtb, Ab);

    // out = attn@wo^T + bo (f32 out), BM=64 -> 512 blocks
    gemm_lds<64, 0, float><<<dim3(DM / 128, SEQ / 64), dim3(256), 0, stream>>>(
        Ab, wob, bo, bo, out, SEQ, DM, DM, 1.0f, 1.0f, 1 << 30);
}